// Round 3
// baseline (329.696 us; speedup 1.0000x reference)
//
#include <hip/hip_runtime.h>

typedef unsigned int u32;
typedef unsigned short u16;
typedef short s8v __attribute__((ext_vector_type(8)));     // 8 bf16 = 4 VGPR
typedef float f16v __attribute__((ext_vector_type(16)));   // 32x32 accumulator

#define NB 4
#define NC 128
#define HW 12288
#define NS 1024

// resp = exp(20*(0.5*corr + 0.5 - 0.9995)) = exp(10*corr - 9.99)
#define EXP_A 10.0f
#define EXP_B (-9.99f)

#define TS 256            // s-tile per block
#define TP 256            // px-tile per block
#define NPT (HW/TP)       // 48
#define NST (NS/TS)       // 4

__device__ inline u16 f2bf(float f) {            // RNE fp32->bf16
    u32 u = __float_as_uint(f);
    return (u16)((u + 0x7fffu + ((u >> 16) & 1u)) >> 16);
}
__device__ inline float bf2f(u16 h) { return __uint_as_float(((u32)h) << 16); }

__device__ inline void gload_lds16(const void* g, void* l) {
    __builtin_amdgcn_global_load_lds(
        (const __attribute__((address_space(1))) void*)g,
        (__attribute__((address_space(3))) void*)l, 16, 0, 0);
}

// ---------------------------------------------------------------------------
// prep (fused): blocks [0,768) transform tgt -> Bq hi/lo (bank-swizzled);
// blocks [768,2816) gather sampled vectors -> As hi/lo and zero sums.
// Fusing lets the scattered gather overlap the streaming transform.
// ---------------------------------------------------------------------------
__global__ __launch_bounds__(256) void prep(
    const float* __restrict__ src, const float* __restrict__ tgt,
    const int* __restrict__ loc,
    u16* __restrict__ ahi, u16* __restrict__ alo,
    u16* __restrict__ bhi, u16* __restrict__ blo,
    float* __restrict__ sums)
{
    int blk = blockIdx.x, t = threadIdx.x;
    if (blk < (HW / 64) * NB) {
        // ---- target prep: tgt [b][c][px] fp32 -> Bq[b][kc][px][slot][8] hi/lo
        int b = blk / (HW / 64), pt = blk - b * (HW / 64);
        int pxl = t & 63, u = t >> 6;
        int px = pt * 64 + pxl;
        int slot = u ^ ((px >> 1) & 3);
#pragma unroll
        for (int kc = 0; kc < 4; ++kc) {
            int c0 = kc * 32 + u * 8;
            u32 hq[4], lq[4];
#pragma unroll
            for (int k = 0; k < 4; ++k) {
                float v0 = tgt[((size_t)(b * NC + c0 + 2 * k)) * HW + px];
                float v1 = tgt[((size_t)(b * NC + c0 + 2 * k + 1)) * HW + px];
                u16 h0 = f2bf(v0), h1 = f2bf(v1);
                u16 l0 = f2bf(v0 - bf2f(h0)), l1 = f2bf(v1 - bf2f(h1));
                hq[k] = (u32)h0 | ((u32)h1 << 16);
                lq[k] = (u32)l0 | ((u32)l1 << 16);
            }
            size_t off = (((size_t)((b * 4 + kc) * HW + px)) * 4 + slot) * 8;  // u16 units
            *(uint4*)(bhi + off) = make_uint4(hq[0], hq[1], hq[2], hq[3]);
            *(uint4*)(blo + off) = make_uint4(lq[0], lq[1], lq[2], lq[3]);
        }
    } else {
        // ---- sample gather + zero sums
        int sb = blk - (HW / 64) * NB;
        int gid = sb * 256 + t;
        if (gid < NB * NS) sums[gid] = 0.0f;
        int bs = sb * 2 + (t >> 7);
        int c  = t & 127;
        int b  = bs >> 10, s = bs & 1023;
        int l  = loc[bs];
        float v = src[((size_t)(b * NC + c)) * HW + l];
        u16 h  = f2bf(v);
        u16 lo = f2bf(v - bf2f(h));
        int kc = c >> 5, u = (c >> 3) & 3, e = c & 7;
        int slot = u ^ ((s >> 1) & 3);
        size_t off = ((size_t)((b * 4 + kc) * NS + s)) * 32 + slot * 8 + e;
        ahi[off] = h;
        alo[off] = lo;
    }
}

// ---------------------------------------------------------------------------
// corr_fused: split-bf16 MFMA GEMM, 256s x 256px block tile, 8 waves.
// SINGLE pass (replaces the old two-pass corr2<0>/corr2<1>): stores
// unnormalized e = exp(10*corr-9.99)*mask to out AND accumulates per-row
// sums (LDS reduce + 1 atomic per (row,half)). Normalization happens in the
// bandwidth-bound rescale kernel. Same verified 2-phase schedule as the
// baseline: single 64 KB LDS buffer, __syncthreads() only (no raw barriers,
// no inline waitcnt). T5 setprio around the MFMA cluster (hint-only).
// XCD swizzle: blocks sharing a B-tile (same pt,b; st=0..3) get ids 8 apart.
// ---------------------------------------------------------------------------
__global__ __launch_bounds__(512) void corr_fused(
    const u16* __restrict__ bhi, const u16* __restrict__ blo,
    const u16* __restrict__ ahi, const u16* __restrict__ alo,
    const float* __restrict__ mask, float* __restrict__ sums,
    float* __restrict__ out)
{
    __shared__ __align__(1024) char sm[65536];   // [rg 4][row 256][slot 4][16B]

    // Decode block id with XCD-aware swizzle (xcd = id & 7 heuristic).
    int f = blockIdx.x;
    int xcd = f & 7, r0 = f >> 3;          // r0: 0..95
    int st = r0 & 3;
    int p  = (r0 >> 2) * 8 + xcd;          // 0..191
    int b  = p / 48, pt = p - b * 48;      // pt: 0..47

    int t = threadIdx.x, w = t >> 6, l = t & 63, ln = l & 31, h = l >> 5;
    int ws = w >> 1, wp = w & 1;

    f16v acc[2][4];
#pragma unroll
    for (int i = 0; i < 2; ++i)
#pragma unroll
        for (int j = 0; j < 4; ++j)
#pragma unroll
            for (int r = 0; r < 16; ++r) acc[i][j][r] = 0.0f;

    for (int kc = 0; kc < 4; ++kc) {
        const char* ga_h = (const char*)ahi + ((size_t)((b * 4 + kc) * NS + st * TS)) * 64;
        const char* ga_l = (const char*)alo + ((size_t)((b * 4 + kc) * NS + st * TS)) * 64;
        const char* gb_h = (const char*)bhi + ((size_t)((b * 4 + kc) * HW + pt * TP)) * 64;
        const char* gb_l = (const char*)blo + ((size_t)((b * 4 + kc) * HW + pt * TP)) * 64;
        // Stage 4 x 16 KB regions; 64 wave-chunks of 1 KB, 8 per wave.
#pragma unroll
        for (int it = 0; it < 8; ++it) {
            int q = w * 8 + it;                // wave-uniform
            int rg = q >> 4, inner = q & 15;
            const char* gb = rg == 0 ? ga_h : rg == 1 ? ga_l : rg == 2 ? gb_h : gb_l;
            gload_lds16(gb + inner * 1024 + l * 16, sm + q * 1024);
        }
        __syncthreads();

#pragma unroll
        for (int kk2 = 0; kk2 < 2; ++kk2) {
            int u = kk2 * 2 + h;               // 16B unit within 32-k chunk
            s8v a_h[2], a_l[2], b_h[4], b_l[4];
#pragma unroll
            for (int i = 0; i < 2; ++i) {
                int row = ws * 64 + i * 32 + ln;
                int sl = u ^ ((row >> 1) & 3);
                a_h[i] = *(const s8v*)(sm + 0 * 16384 + row * 64 + sl * 16);
                a_l[i] = *(const s8v*)(sm + 1 * 16384 + row * 64 + sl * 16);
            }
#pragma unroll
            for (int j = 0; j < 4; ++j) {
                int px = wp * 128 + j * 32 + ln;
                int sl = u ^ ((px >> 1) & 3);
                b_h[j] = *(const s8v*)(sm + 2 * 16384 + px * 64 + sl * 16);
                b_l[j] = *(const s8v*)(sm + 3 * 16384 + px * 64 + sl * 16);
            }
            __builtin_amdgcn_s_setprio(1);
#pragma unroll
            for (int i = 0; i < 2; ++i)
#pragma unroll
                for (int j = 0; j < 4; ++j) {
                    acc[i][j] = __builtin_amdgcn_mfma_f32_32x32x16_bf16(a_h[i], b_h[j], acc[i][j], 0, 0, 0);
                    acc[i][j] = __builtin_amdgcn_mfma_f32_32x32x16_bf16(a_l[i], b_h[j], acc[i][j], 0, 0, 0);
                    acc[i][j] = __builtin_amdgcn_mfma_f32_32x32x16_bf16(a_h[i], b_l[j], acc[i][j], 0, 0, 0);
                }
            __builtin_amdgcn_s_setprio(0);
        }
        __syncthreads();   // protect sm before next chunk / epilogue reuse
    }

    // Epilogue. C/D layout: col = ln (px), row_local = (r&3) + 8*(r>>2) + 4*h.
    float mv[4];
#pragma unroll
    for (int j = 0; j < 4; ++j)
        mv[j] = mask[(size_t)b * HW + pt * TP + wp * 128 + j * 32 + ln];

    float* rs = (float*)sm;     // [wp 2][row 256][ln 32] = 64 KB exactly (loop done)
    float* ob0 = out + ((size_t)(b * NS + st * TS)) * HW + pt * TP + wp * 128 + ln;
#pragma unroll
    for (int i = 0; i < 2; ++i) {
        int rb = ws * 64 + i * 32 + 4 * h;
#pragma unroll
        for (int r = 0; r < 16; ++r) {
            int row = rb + (r & 3) + 8 * (r >> 2);
            float tot = 0.0f;
#pragma unroll
            for (int j = 0; j < 4; ++j) {
                float e = __expf(fmaf(acc[i][j][r], EXP_A, EXP_B)) * mv[j];
                ob0[(size_t)row * HW + j * 32] = e;     // unnormalized store
                tot += e;
            }
            rs[(wp * TS + row) * 32 + ln] = tot;
        }
    }
    __syncthreads();
    int row2 = t & 255, half = t >> 8;
    float tot = 0.0f;
#pragma unroll
    for (int c = 0; c < 32; ++c)
        tot += rs[(half * TS + row2) * 32 + ((c + t) & 31)];  // rotated: no bank conflict
    atomicAdd(&sums[b * NS + st * TS + row2], tot);
}

// ---------------------------------------------------------------------------
// rescale: out[b,s,:] *= 1/sums[b,s]. One block per row; 402 MB streaming,
// reads mostly L3-resident (just written by corr_fused).
// ---------------------------------------------------------------------------
__global__ __launch_bounds__(256) void rescale(
    const float* __restrict__ sums, float* __restrict__ out)
{
    int bs = blockIdx.x;                       // 0..4095 = b*NS + s
    float inv = 1.0f / sums[bs];
    float4* p = (float4*)(out + (size_t)bs * HW);
    int t = threadIdx.x;
#pragma unroll
    for (int i = 0; i < 12; ++i) {             // HW/4 = 3072 float4 per row
        float4 v = p[t + i * 256];
        v.x *= inv; v.y *= inv; v.z *= inv; v.w *= inv;
        p[t + i * 256] = v;
    }
}

extern "C" void kernel_launch(void* const* d_in, const int* in_sizes, int n_in,
                              void* d_out, int out_size, void* d_ws, size_t ws_size,
                              hipStream_t stream) {
    const float* src  = (const float*)d_in[0];
    const float* tgt  = (const float*)d_in[1];
    const int*   loc  = (const int*)d_in[2];
    const float* mask = (const float*)d_in[3];
    float* out = (float*)d_out;

    char* ws = (char*)d_ws;
    const size_t BPLANE = (size_t)NB * 4 * HW * 32 * sizeof(u16);  // 12.58 MB
    const size_t APLANE = (size_t)NB * 4 * NS * 32 * sizeof(u16);  //  1.05 MB
    u16* bhi = (u16*)ws;
    u16* blo = (u16*)(ws + BPLANE);
    u16* ahi = (u16*)(ws + 2 * BPLANE);
    u16* alo = (u16*)(ws + 2 * BPLANE + APLANE);
    float* sums = (float*)(ws + 2 * BPLANE + 2 * APLANE);          // 16 KB

    prep<<<dim3((HW / 64) * NB + NB * NS / 2), 256, 0, stream>>>(
        src, tgt, loc, ahi, alo, bhi, blo, sums);

    dim3 g(NPT * NST * NB);   // 768 flat, decoded with XCD swizzle in-kernel
    corr_fused<<<g, 512, 0, stream>>>(bhi, blo, ahi, alo, mask, sums, out);

    rescale<<<dim3(NB * NS), 256, 0, stream>>>(sums, out);
}

// Round 4
// 325.734 us; speedup vs baseline: 1.0122x; 1.0122x over previous
//
#include <hip/hip_runtime.h>

typedef unsigned int u32;
typedef unsigned short u16;
typedef short s8v __attribute__((ext_vector_type(8)));     // 8 bf16 = 4 VGPR
typedef float f16v __attribute__((ext_vector_type(16)));   // 32x32 accumulator
typedef _Float16 h8 __attribute__((ext_vector_type(8)));   // 8 fp16 = 16 B

#define NB 4
#define NC 128
#define HW 12288
#define NS 1024

// resp = exp(20*(0.5*corr + 0.5 - 0.9995)) = exp(10*corr - 9.99)
#define EXP_A 10.0f
#define EXP_B (-9.99f)
#define ESCALE 4096.0f    // power of 2: e*ESCALE is exact in fp32, cancels in e/sum

#define TS 256            // s-tile per block
#define TP 256            // px-tile per block
#define NPT (HW/TP)       // 48
#define NST (NS/TS)       // 4

__device__ inline u16 f2bf(float f) {            // RNE fp32->bf16
    u32 u = __float_as_uint(f);
    return (u16)((u + 0x7fffu + ((u >> 16) & 1u)) >> 16);
}
__device__ inline float bf2f(u16 h) { return __uint_as_float(((u32)h) << 16); }

__device__ inline void gload_lds16(const void* g, void* l) {
    __builtin_amdgcn_global_load_lds(
        (const __attribute__((address_space(1))) void*)g,
        (__attribute__((address_space(3))) void*)l, 16, 0, 0);
}

// ---------------------------------------------------------------------------
// prep (fused): blocks [0,768) transform tgt -> Bq hi/lo (bank-swizzled);
// blocks [768,2816) gather sampled vectors -> As hi/lo and zero sums.
// ---------------------------------------------------------------------------
__global__ __launch_bounds__(256) void prep(
    const float* __restrict__ src, const float* __restrict__ tgt,
    const int* __restrict__ loc,
    u16* __restrict__ ahi, u16* __restrict__ alo,
    u16* __restrict__ bhi, u16* __restrict__ blo,
    float* __restrict__ sums)
{
    int blk = blockIdx.x, t = threadIdx.x;
    if (blk < (HW / 64) * NB) {
        // ---- target prep: tgt [b][c][px] fp32 -> Bq[b][kc][px][slot][8] hi/lo
        int b = blk / (HW / 64), pt = blk - b * (HW / 64);
        int pxl = t & 63, u = t >> 6;
        int px = pt * 64 + pxl;
        int slot = u ^ ((px >> 1) & 3);
#pragma unroll
        for (int kc = 0; kc < 4; ++kc) {
            int c0 = kc * 32 + u * 8;
            u32 hq[4], lq[4];
#pragma unroll
            for (int k = 0; k < 4; ++k) {
                float v0 = tgt[((size_t)(b * NC + c0 + 2 * k)) * HW + px];
                float v1 = tgt[((size_t)(b * NC + c0 + 2 * k + 1)) * HW + px];
                u16 h0 = f2bf(v0), h1 = f2bf(v1);
                u16 l0 = f2bf(v0 - bf2f(h0)), l1 = f2bf(v1 - bf2f(h1));
                hq[k] = (u32)h0 | ((u32)h1 << 16);
                lq[k] = (u32)l0 | ((u32)l1 << 16);
            }
            size_t off = (((size_t)((b * 4 + kc) * HW + px)) * 4 + slot) * 8;  // u16 units
            *(uint4*)(bhi + off) = make_uint4(hq[0], hq[1], hq[2], hq[3]);
            *(uint4*)(blo + off) = make_uint4(lq[0], lq[1], lq[2], lq[3]);
        }
    } else {
        // ---- sample gather + zero sums
        int sb = blk - (HW / 64) * NB;
        int gid = sb * 256 + t;
        if (gid < NB * NS) sums[gid] = 0.0f;
        int bs = sb * 2 + (t >> 7);
        int c  = t & 127;
        int b  = bs >> 10, s = bs & 1023;
        int l  = loc[bs];
        float v = src[((size_t)(b * NC + c)) * HW + l];
        u16 h  = f2bf(v);
        u16 lo = f2bf(v - bf2f(h));
        int kc = c >> 5, u = (c >> 3) & 3, e = c & 7;
        int slot = u ^ ((s >> 1) & 3);
        size_t off = ((size_t)((b * 4 + kc) * NS + s)) * 32 + slot * 8 + e;
        ahi[off] = h;
        alo[off] = lo;
    }
}

// ---------------------------------------------------------------------------
// corr_fused<F16>: split-bf16 MFMA GEMM, 256s x 256px tile, 8 waves, single
// pass. Stores unnormalized e (scaled by ESCALE) and accumulates per-row
// sums of the SAME scaled fp32 values (scale cancels exactly at rescale).
// F16=1: e -> fp16 plane in ws (halves intermediate HBM traffic).
// F16=0: e -> fp32 in-place in out (fallback when ws too small).
// Verified 2-phase schedule: single 64 KB LDS buffer, __syncthreads() only.
// ---------------------------------------------------------------------------
template <int F16>
__global__ __launch_bounds__(512) void corr_fused(
    const u16* __restrict__ bhi, const u16* __restrict__ blo,
    const u16* __restrict__ ahi, const u16* __restrict__ alo,
    const float* __restrict__ mask, float* __restrict__ sums,
    _Float16* __restrict__ ebuf, float* __restrict__ out)
{
    __shared__ __align__(1024) char sm[65536];   // [rg 4][row 256][slot 4][16B]

    // Decode block id with XCD-aware swizzle (xcd = id & 7 heuristic).
    int f = blockIdx.x;
    int xcd = f & 7, r0 = f >> 3;          // r0: 0..95
    int st = r0 & 3;
    int p  = (r0 >> 2) * 8 + xcd;          // 0..191
    int b  = p / 48, pt = p - b * 48;      // pt: 0..47

    int t = threadIdx.x, w = t >> 6, l = t & 63, ln = l & 31, h = l >> 5;
    int ws = w >> 1, wp = w & 1;

    f16v acc[2][4];
#pragma unroll
    for (int i = 0; i < 2; ++i)
#pragma unroll
        for (int j = 0; j < 4; ++j)
#pragma unroll
            for (int r = 0; r < 16; ++r) acc[i][j][r] = 0.0f;

    for (int kc = 0; kc < 4; ++kc) {
        const char* ga_h = (const char*)ahi + ((size_t)((b * 4 + kc) * NS + st * TS)) * 64;
        const char* ga_l = (const char*)alo + ((size_t)((b * 4 + kc) * NS + st * TS)) * 64;
        const char* gb_h = (const char*)bhi + ((size_t)((b * 4 + kc) * HW + pt * TP)) * 64;
        const char* gb_l = (const char*)blo + ((size_t)((b * 4 + kc) * HW + pt * TP)) * 64;
        // Stage 4 x 16 KB regions; 64 wave-chunks of 1 KB, 8 per wave.
#pragma unroll
        for (int it = 0; it < 8; ++it) {
            int q = w * 8 + it;                // wave-uniform
            int rg = q >> 4, inner = q & 15;
            const char* gb = rg == 0 ? ga_h : rg == 1 ? ga_l : rg == 2 ? gb_h : gb_l;
            gload_lds16(gb + inner * 1024 + l * 16, sm + q * 1024);
        }
        __syncthreads();

#pragma unroll
        for (int kk2 = 0; kk2 < 2; ++kk2) {
            int u = kk2 * 2 + h;               // 16B unit within 32-k chunk
            s8v a_h[2], a_l[2], b_h[4], b_l[4];
#pragma unroll
            for (int i = 0; i < 2; ++i) {
                int row = ws * 64 + i * 32 + ln;
                int sl = u ^ ((row >> 1) & 3);
                a_h[i] = *(const s8v*)(sm + 0 * 16384 + row * 64 + sl * 16);
                a_l[i] = *(const s8v*)(sm + 1 * 16384 + row * 64 + sl * 16);
            }
#pragma unroll
            for (int j = 0; j < 4; ++j) {
                int px = wp * 128 + j * 32 + ln;
                int sl = u ^ ((px >> 1) & 3);
                b_h[j] = *(const s8v*)(sm + 2 * 16384 + px * 64 + sl * 16);
                b_l[j] = *(const s8v*)(sm + 3 * 16384 + px * 64 + sl * 16);
            }
            __builtin_amdgcn_s_setprio(1);
#pragma unroll
            for (int i = 0; i < 2; ++i)
#pragma unroll
                for (int j = 0; j < 4; ++j) {
                    acc[i][j] = __builtin_amdgcn_mfma_f32_32x32x16_bf16(a_h[i], b_h[j], acc[i][j], 0, 0, 0);
                    acc[i][j] = __builtin_amdgcn_mfma_f32_32x32x16_bf16(a_l[i], b_h[j], acc[i][j], 0, 0, 0);
                    acc[i][j] = __builtin_amdgcn_mfma_f32_32x32x16_bf16(a_h[i], b_l[j], acc[i][j], 0, 0, 0);
                }
            __builtin_amdgcn_s_setprio(0);
        }
        __syncthreads();   // protect sm before next chunk / epilogue reuse
    }

    // Epilogue. C/D layout: col = ln (px), row_local = (r&3) + 8*(r>>2) + 4*h.
    // mvs = mask * ESCALE (exact power-of-2 scale, cancels at rescale).
    float mvs[4];
#pragma unroll
    for (int j = 0; j < 4; ++j)
        mvs[j] = mask[(size_t)b * HW + pt * TP + wp * 128 + j * 32 + ln] * ESCALE;

    float* rs = (float*)sm;     // [wp 2][row 256][ln 32] = 64 KB exactly (loop done)
    size_t base = ((size_t)(b * NS + st * TS)) * HW + pt * TP + wp * 128 + ln;
    _Float16* eb0 = ebuf + base;
    float*    ob0 = out  + base;
#pragma unroll
    for (int i = 0; i < 2; ++i) {
        int rb = ws * 64 + i * 32 + 4 * h;
#pragma unroll
        for (int r = 0; r < 16; ++r) {
            int row = rb + (r & 3) + 8 * (r >> 2);
            float tot = 0.0f;
#pragma unroll
            for (int j = 0; j < 4; ++j) {
                float e = __expf(fmaf(acc[i][j][r], EXP_A, EXP_B)) * mvs[j];
                if (F16) eb0[(size_t)row * HW + j * 32] = (_Float16)e;
                else     ob0[(size_t)row * HW + j * 32] = e;
                tot += e;
            }
            rs[(wp * TS + row) * 32 + ln] = tot;
        }
    }
    __syncthreads();
    int row2 = t & 255, half = t >> 8;
    float tot = 0.0f;
#pragma unroll
    for (int c = 0; c < 32; ++c)
        tot += rs[(half * TS + row2) * 32 + ((c + t) & 31)];  // rotated: no bank conflict
    atomicAdd(&sums[b * NS + st * TS + row2], tot);
}

// ---------------------------------------------------------------------------
// rescale16: out[b,s,:] = fp16 e[b,s,:] / sums[b,s]. 100.7 MB read (mostly
// L2/L3-resident, just written) + 201 MB write.
// ---------------------------------------------------------------------------
__global__ __launch_bounds__(256) void rescale16(
    const float* __restrict__ sums, const _Float16* __restrict__ ebuf,
    float* __restrict__ out)
{
    int bs = blockIdx.x;                       // 0..4095 = b*NS + s
    float inv = 1.0f / sums[bs];
    const h8* p = (const h8*)(ebuf + (size_t)bs * HW);
    float4* o = (float4*)(out + (size_t)bs * HW);
    int t = threadIdx.x;
#pragma unroll
    for (int i = 0; i < 6; ++i) {              // HW/8 = 1536 h8 per row
        int idx = t + i * 256;
        h8 v = p[idx];
        float4 a, c;
        a.x = (float)v[0] * inv; a.y = (float)v[1] * inv;
        a.z = (float)v[2] * inv; a.w = (float)v[3] * inv;
        c.x = (float)v[4] * inv; c.y = (float)v[5] * inv;
        c.z = (float)v[6] * inv; c.w = (float)v[7] * inv;
        o[2 * idx]     = a;
        o[2 * idx + 1] = c;
    }
}

// Fallback: in-place fp32 rescale (round-3 verified path).
__global__ __launch_bounds__(256) void rescale32(
    const float* __restrict__ sums, float* __restrict__ out)
{
    int bs = blockIdx.x;
    float inv = 1.0f / sums[bs];
    float4* p = (float4*)(out + (size_t)bs * HW);
    int t = threadIdx.x;
#pragma unroll
    for (int i = 0; i < 12; ++i) {
        float4 v = p[t + i * 256];
        v.x *= inv; v.y *= inv; v.z *= inv; v.w *= inv;
        p[t + i * 256] = v;
    }
}

extern "C" void kernel_launch(void* const* d_in, const int* in_sizes, int n_in,
                              void* d_out, int out_size, void* d_ws, size_t ws_size,
                              hipStream_t stream) {
    const float* src  = (const float*)d_in[0];
    const float* tgt  = (const float*)d_in[1];
    const int*   loc  = (const int*)d_in[2];
    const float* mask = (const float*)d_in[3];
    float* out = (float*)d_out;

    char* ws = (char*)d_ws;
    const size_t BPLANE = (size_t)NB * 4 * HW * 32 * sizeof(u16);  // 12.58 MB
    const size_t APLANE = (size_t)NB * 4 * NS * 32 * sizeof(u16);  //  1.05 MB
    const size_t EPLANE = (size_t)NB * NS * HW * sizeof(_Float16); // 100.7 MB
    u16* bhi = (u16*)ws;
    u16* blo = (u16*)(ws + BPLANE);
    u16* ahi = (u16*)(ws + 2 * BPLANE);
    u16* alo = (u16*)(ws + 2 * BPLANE + APLANE);
    float* sums = (float*)(ws + 2 * BPLANE + 2 * APLANE);          // 16 KB used
    _Float16* ebuf = (_Float16*)(ws + 2 * BPLANE + 2 * APLANE + 65536);
    const size_t NEED = 2 * BPLANE + 2 * APLANE + 65536 + EPLANE;  // ~128 MB

    prep<<<dim3((HW / 64) * NB + NB * NS / 2), 256, 0, stream>>>(
        src, tgt, loc, ahi, alo, bhi, blo, sums);

    dim3 g(NPT * NST * NB);   // 768 flat, decoded with XCD swizzle in-kernel
    if (ws_size >= NEED) {
        corr_fused<1><<<g, 512, 0, stream>>>(bhi, blo, ahi, alo, mask, sums, ebuf, out);
        rescale16<<<dim3(NB * NS), 256, 0, stream>>>(sums, ebuf, out);
    } else {
        corr_fused<0><<<g, 512, 0, stream>>>(bhi, blo, ahi, alo, mask, sums, ebuf, out);
        rescale32<<<dim3(NB * NS), 256, 0, stream>>>(sums, out);
    }
}